// Round 1
// baseline (331.829 us; speedup 1.0000x reference)
//
#include <hip/hip_runtime.h>
#include <math.h>

#define B_ 64
#define N_ 512
#define P_ 256
#define E_ 4096
#define F_ 32
#define H_ 64
#define W_ 8
#define G_ 64
#define RH_ 256

// ---- workspace layout (float offsets) ----
#define X_OFF   0
#define T4_OFF  (X_OFF + N_*B_*F_)       // x:  [n][b][f]
#define T3_OFF  (T4_OFF + N_*B_*H_)      // t4: [n][b][h] (t2 folded in)
#define KB_OFF  (T3_OFF + P_*B_*H_)      // t3: [p][b][h]
#define KW_OFF  (KB_OFF + E_*H_)         // kb: [e][h]
#define YG_OFF  (KW_OFF + E_*B_*W_)      // (kw slot unused now, kept for layout stability)
#define HB_OFF  (YG_OFF + B_*P_*G_)      // yg: [b][p*64+g]
#define RES_OFF (HB_OFF + B_*RH_)        // hbuf: [b][rh]
#define INT_OFF (RES_OFF + 4*B_*G_)      // res4: [pq][b][g]
// int region at INT_OFF: lidx[4096] | ridx[4096] | part_start[512] | part_edges[4096]
// r0 partials (256*16384 floats = 16 MB) alias X_OFF.. (x/t4/t3/kb dead after k_eagg)

// ---------------------------------------------------------------------------
__global__ __launch_bounds__(256) void k_decode(const float* __restrict__ linc,
    const float* __restrict__ rinc, int* __restrict__ lidx, int* __restrict__ ridx) {
  int i4 = blockIdx.x * 256 + threadIdx.x;
  const int L4 = (P_ * E_) / 4;  // 262144
  if (i4 < L4) {
    float4 v = ((const float4*)linc)[i4];
    int i = i4 * 4;
    int p = i >> 12, e = i & 4095;
    if (v.x != 0.0f) lidx[e]     = p;
    if (v.y != 0.0f) lidx[e + 1] = p;
    if (v.z != 0.0f) lidx[e + 2] = p;
    if (v.w != 0.0f) lidx[e + 3] = p;
  } else {
    int j4 = i4 - L4;
    float4 v = ((const float4*)rinc)[j4];
    int j = j4 * 4;
    int e = j >> 9, n = j & 511;
    if (v.x != 0.0f) ridx[e] = n;
    if (v.y != 0.0f) ridx[e] = n + 1;
    if (v.z != 0.0f) ridx[e] = n + 2;
    if (v.w != 0.0f) ridx[e] = n + 3;
  }
}

// Counting-sort edges by partition. Single block of 1024.
__global__ __launch_bounds__(1024) void k_lists(const int* __restrict__ lidx,
    int* __restrict__ part_start, int* __restrict__ part_edges) {
  __shared__ int cnt[256];
  __shared__ int buf[256];
  __shared__ int cur[256];
  int t = threadIdx.x;
  if (t < 256) cnt[t] = 0;
  __syncthreads();
  for (int e = t; e < E_; e += 1024) atomicAdd(&cnt[lidx[e]], 1);
  __syncthreads();
  if (t < 256) buf[t] = cnt[t];
  __syncthreads();
  for (int off = 1; off < 256; off <<= 1) {
    int add = 0;
    if (t < 256 && t >= off) add = buf[t - off];
    __syncthreads();
    if (t < 256) buf[t] += add;
    __syncthreads();
  }
  if (t < 256) {
    part_start[t + 1] = buf[t];
    if (t == 0) part_start[0] = 0;
    cur[t] = buf[t] - cnt[t];
  }
  __syncthreads();
  for (int e = t; e < E_; e += 1024) {
    int p = lidx[e];
    int pos = atomicAdd(&cur[p], 1);
    part_edges[pos] = e;
  }
}

// Grouped conv (K=16, VALID, 1 out pos) + bias + relu -> x[n][b][f]
__global__ __launch_bounds__(256) void k_conv(const float* __restrict__ x1,
    const float* __restrict__ conv_w, const float* __restrict__ conv_b,
    float* __restrict__ x) {
  __shared__ float wsm[32 * 132];
  __shared__ float xsm[8192];
  int n = blockIdx.x, t = threadIdx.x;
  for (int i = t; i < 1024; i += 256) {
    int f = i >> 5, j = i & 31;
    ((float4*)wsm)[f * 33 + j] = ((const float4*)(conv_w + n * 4096))[i];
  }
  for (int i = t; i < 2048; i += 256) {
    int b = i >> 5, j = i & 31;
    ((float4*)xsm)[i] = ((const float4*)(x1 + b * 65536 + n * 128))[j];
  }
  __syncthreads();
  int f = t & 31, bq = t >> 5;
  float cb = conv_b[n * 32 + f];
  float acc[8];
#pragma unroll
  for (int bi = 0; bi < 8; bi++) acc[bi] = cb;
  const float4* wf4 = (const float4*)wsm + f * 33;
  const float4* xb4 = (const float4*)xsm + bq * 256;
#pragma unroll 4
  for (int k4 = 0; k4 < 32; k4++) {
    float4 wv = wf4[k4];
#pragma unroll
    for (int bi = 0; bi < 8; bi++) {
      float4 xv = xb4[bi * 32 + k4];
      acc[bi] += wv.x * xv.x + wv.y * xv.y + wv.z * xv.z + wv.w * xv.w;
    }
  }
#pragma unroll
  for (int bi = 0; bi < 8; bi++) {
    int b = bq * 8 + bi;
    x[n * 2048 + b * 32 + f] = fmaxf(acc[bi], 0.0f);
  }
}

// blocks [0,512): t4[n][b][h] = x[n]@k4_w^T + x2@k2_w^T
// blocks [512,768): t3[p][b][h] = x[pidx[p]]@k3_w^T
// blocks [768,1792): kb[e][h] = ef[e,:8]@k1_w^T + k1_b
// blocks [1792,1856): hbuf[b][rh] = x2@r1_w^T + r1_b + cap@r2_w^T
__global__ __launch_bounds__(256) void k_prep(
    const float* __restrict__ x, const int* __restrict__ pidx,
    const float* __restrict__ k3_w, const float* __restrict__ k4_w,
    const float* __restrict__ x2, const float* __restrict__ k2_w,
    const float* __restrict__ ef, const float* __restrict__ k1_w,
    const float* __restrict__ k1_b,
    const float* __restrict__ r1_w, const float* __restrict__ r1_b,
    const float* __restrict__ r2_w, const float* __restrict__ cap,
    float* __restrict__ t4, float* __restrict__ t3, float* __restrict__ kb,
    float* __restrict__ hbuf) {
  __shared__ float xsh[2048];
  __shared__ float wsh[64 * 36];
  __shared__ float x2s[512];
  __shared__ float k2s[512];
  int blk = blockIdx.x, t = threadIdx.x;
  if (blk < 768) {
    bool isT4 = blk < 512;
    int n = isT4 ? blk : pidx[blk - 512];
    const float* wmat = isT4 ? k4_w : k3_w;
    float* outp = isT4 ? (t4 + blk * 4096) : (t3 + (blk - 512) * 4096);
    for (int i = t; i < 512; i += 256) {
      ((float4*)xsh)[i] = ((const float4*)(x + n * 2048))[i];
      int h = i >> 3, j = i & 7;
      ((float4*)wsh)[h * 9 + j] = ((const float4*)wmat)[i];
    }
    if (isT4) {
      for (int i = t; i < 128; i += 256) {
        ((float4*)x2s)[i] = ((const float4*)x2)[i];
        ((float4*)k2s)[i] = ((const float4*)k2_w)[i];
      }
    }
    __syncthreads();
    int h = t & 63, bq = t >> 6;
    float wreg[32];
#pragma unroll
    for (int j = 0; j < 8; j++) {
      float4 v = ((float4*)wsh)[h * 9 + j];
      wreg[4 * j] = v.x; wreg[4 * j + 1] = v.y; wreg[4 * j + 2] = v.z; wreg[4 * j + 3] = v.w;
    }
    float w2[8];
    if (isT4) {
      float4 u = ((float4*)k2s)[h * 2], v = ((float4*)k2s)[h * 2 + 1];
      w2[0] = u.x; w2[1] = u.y; w2[2] = u.z; w2[3] = u.w;
      w2[4] = v.x; w2[5] = v.y; w2[6] = v.z; w2[7] = v.w;
    }
    for (int bi = 0; bi < 16; bi++) {
      int b = bq * 16 + bi;
      float acc = 0.0f;
#pragma unroll
      for (int j = 0; j < 8; j++) {
        float4 xv = ((float4*)xsh)[b * 8 + j];
        acc += xv.x * wreg[4 * j] + xv.y * wreg[4 * j + 1] +
               xv.z * wreg[4 * j + 2] + xv.w * wreg[4 * j + 3];
      }
      if (isT4) {
        float4 u = ((float4*)x2s)[b * 2], v = ((float4*)x2s)[b * 2 + 1];
        acc += u.x * w2[0] + u.y * w2[1] + u.z * w2[2] + u.w * w2[3] +
               v.x * w2[4] + v.y * w2[5] + v.z * w2[6] + v.w * w2[7];
      }
      outp[b * 64 + h] = acc;
    }
  } else if (blk < 1792) {
    int o = (blk - 768) * 256 + t;
    int e = o >> 6, h = o & 63;
    float acc = k1_b[h];
    const float* er = ef + e * 9;
    const float* kr = k1_w + h * 8;
#pragma unroll
    for (int d = 0; d < 8; d++) acc += er[d] * kr[d];
    kb[o] = acc;
  } else {
    int o = (blk - 1792) * 256 + t;
    int rh = o & 255;
    float acc = r1_b[rh];
    const float* xr = x2 + (o >> 8) * 8;
    const float* rr = r1_w + rh * 8;
#pragma unroll
    for (int d = 0; d < 8; d++) acc += xr[d] * rr[d];
    const float* r2r = r2_w + rh * 256;
    for (int p4 = 0; p4 < 64; p4++) {
      float4 cv = ((const float4*)cap)[p4];
      float4 rv = ((const float4*)r2r)[p4];
      acc += cv.x * rv.x + cv.y * rv.y + cv.z * rv.z + cv.w * rv.w;
    }
    hbuf[o] = acc;
  }
}

// Fused edge-MLP + aggregation + gc GEMM.
// Grid 1024 = (p 256) x (bh 4): block handles 16 batch rows of partition p.
// Lanes: s = t&15 (h-quarter of 4 h; also selects w-pair j=s&3 and f-group q=s>>2),
//        bl = t>>4 (local b). k5_w fragment + t3 fragment hoisted to registers
// (loop-invariant). Only LDS: accS bf16 [16][256].
__global__ __launch_bounds__(256, 4) void k_eagg(
    const float* __restrict__ x, const float* __restrict__ kb,
    const float* __restrict__ t3, const float* __restrict__ t4,
    const float* __restrict__ k5_w, const float* __restrict__ k5_b,
    const int* __restrict__ ridx, const int* __restrict__ part_start,
    const int* __restrict__ part_edges,
    const float* __restrict__ gc_w, const float* __restrict__ gc_b,
    float* __restrict__ yg) {
  __shared__ unsigned short accS[16 * 256];  // bf16 [bl][k], oct ^ (bl&7) swizzle
  int blk = blockIdx.x;
  int p = blk >> 2, bh = blk & 3;
  int t = threadIdx.x;
  int s = t & 15, bl = t >> 4;
  int bg = bh * 16 + bl;          // global batch row
  int j = s & 3;                  // w-pair {2j, 2j+1}
  int q = s >> 2;                 // f-group: f0 = q*8
  int f0 = q * 8;
  // hoist k5 weights: kr4[w] = k5_w[w][s*4 .. s*4+3]
  float4 kr4[8];
#pragma unroll
  for (int w = 0; w < 8; w++)
    kr4[w] = *(const float4*)(k5_w + w * 64 + s * 4);
  float kb5_0 = k5_b[2 * j], kb5_1 = k5_b[2 * j + 1];
  // loop-invariant t3 fragment for (p, bg, h=s*4..s*4+3)
  float4 t3r = *(const float4*)(t3 + p * 4096 + bg * 64 + s * 4);
  float acc0[8], acc1[8];
#pragma unroll
  for (int i = 0; i < 8; i++) { acc0[i] = 0.0f; acc1[i] = 0.0f; }
  int s0 = part_start[p], s1 = part_start[p + 1];
  int e = 0, r = 0;
  if (s0 < s1) { e = part_edges[s0]; r = ridx[e]; }
  for (int idx = s0; idx < s1; idx++) {
    int e_n = 0, r_n = 0;
    if (idx + 1 < s1) { e_n = part_edges[idx + 1]; r_n = ridx[e_n]; }
    // issue loads early
    const float4* xp = (const float4*)(x + r * 2048 + bg * 32 + f0);
    float4 xv0 = xp[0], xv1 = xp[1];
    float4 a = *(const float4*)(kb + e * 64 + s * 4);
    float4 d = *(const float4*)(t4 + r * 4096 + bg * 64 + s * 4);
    float v, lk0, lk1, lk2, lk3;
    v = a.x + t3r.x + d.x; lk0 = v > 0.0f ? v : 0.02f * v;
    v = a.y + t3r.y + d.y; lk1 = v > 0.0f ? v : 0.02f * v;
    v = a.z + t3r.z + d.z; lk2 = v > 0.0f ? v : 0.02f * v;
    v = a.w + t3r.w + d.w; lk3 = v > 0.0f ? v : 0.02f * v;
    float pw[8];
#pragma unroll
    for (int w = 0; w < 8; w++)
      pw[w] = lk0 * kr4[w].x + lk1 * kr4[w].y + lk2 * kr4[w].z + lk3 * kr4[w].w;
    // reduce over the 16 s-lanes: butterfly bits 0-1, select w-pair, bits 2-3
#pragma unroll
    for (int w = 0; w < 8; w++) {
      pw[w] += __shfl_xor(pw[w], 1);
      pw[w] += __shfl_xor(pw[w], 2);
    }
    float pa = j == 0 ? pw[0] : j == 1 ? pw[2] : j == 2 ? pw[4] : pw[6];
    float pb = j == 0 ? pw[1] : j == 1 ? pw[3] : j == 2 ? pw[5] : pw[7];
    pa += __shfl_xor(pa, 4); pa += __shfl_xor(pa, 8);
    pb += __shfl_xor(pb, 4); pb += __shfl_xor(pb, 8);
    float kv0 = fmaxf(pa + kb5_0, 0.0f);
    float kv1 = fmaxf(pb + kb5_1, 0.0f);
    float xa[8] = {xv0.x, xv0.y, xv0.z, xv0.w, xv1.x, xv1.y, xv1.z, xv1.w};
#pragma unroll
    for (int i = 0; i < 8; i++) acc0[i] += kv0 * xa[i];
#pragma unroll
    for (int i = 0; i < 8; i++) acc1[i] += kv1 * xa[i];
    e = e_n; r = r_n;
  }
  // pack acc -> accS bf16 (RNE). k = w*32 + f0+i  ->  oct = w*4 + q
  {
    unsigned int wds[4];
#pragma unroll
    for (int h = 0; h < 4; h++) {
      unsigned int u0 = __float_as_uint(acc0[2 * h]);
      u0 = u0 + 0x7fffu + ((u0 >> 16) & 1u);
      unsigned int u1 = __float_as_uint(acc0[2 * h + 1]);
      u1 = u1 + 0x7fffu + ((u1 >> 16) & 1u);
      wds[h] = (u0 >> 16) | (u1 & 0xffff0000u);
    }
    int oct = 8 * j + q;          // w = 2j
    int os = oct ^ (bl & 7);
    *(int4*)(accS + bl * 256 + os * 8) =
        make_int4((int)wds[0], (int)wds[1], (int)wds[2], (int)wds[3]);
#pragma unroll
    for (int h = 0; h < 4; h++) {
      unsigned int u0 = __float_as_uint(acc1[2 * h]);
      u0 = u0 + 0x7fffu + ((u0 >> 16) & 1u);
      unsigned int u1 = __float_as_uint(acc1[2 * h + 1]);
      u1 = u1 + 0x7fffu + ((u1 >> 16) & 1u);
      wds[h] = (u0 >> 16) | (u1 & 0xffff0000u);
    }
    oct = 8 * j + 4 + q;          // w = 2j+1
    os = oct ^ (bl & 7);
    *(int4*)(accS + bl * 256 + os * 8) =
        make_int4((int)wds[0], (int)wds[1], (int)wds[2], (int)wds[3]);
  }
  __syncthreads();
  // epilogue: wave wv -> g in [wv*16, wv*16+16); lane: row = lane>>2, 4 g's
  int lane = t & 63, wv = t >> 6;
  int row = lane >> 2;            // local b row 0..15
  int gg = lane & 3;
  int g0 = wv * 16 + gg * 4;
  const float* gw0 = gc_w + g0 * 256;
  const float* gw1 = gw0 + 256;
  const float* gw2 = gw0 + 512;
  const float* gw3 = gw0 + 768;
  float ac0 = 0.0f, ac1 = 0.0f, ac2 = 0.0f, ac3 = 0.0f;
  for (int oct = 0; oct < 32; oct++) {
    int os = oct ^ (row & 7);
    int4 a8 = *(const int4*)(accS + row * 256 + os * 8);
    float4 b0a = *(const float4*)(gw0 + oct * 8);
    float4 b0b = *(const float4*)(gw0 + oct * 8 + 4);
    float4 b1a = *(const float4*)(gw1 + oct * 8);
    float4 b1b = *(const float4*)(gw1 + oct * 8 + 4);
    float4 b2a = *(const float4*)(gw2 + oct * 8);
    float4 b2b = *(const float4*)(gw2 + oct * 8 + 4);
    float4 b3a = *(const float4*)(gw3 + oct * 8);
    float4 b3b = *(const float4*)(gw3 + oct * 8 + 4);
    float bv0[8] = {b0a.x, b0a.y, b0a.z, b0a.w, b0b.x, b0b.y, b0b.z, b0b.w};
    float bv1[8] = {b1a.x, b1a.y, b1a.z, b1a.w, b1b.x, b1b.y, b1b.z, b1b.w};
    float bv2[8] = {b2a.x, b2a.y, b2a.z, b2a.w, b2b.x, b2b.y, b2b.z, b2b.w};
    float bv3[8] = {b3a.x, b3a.y, b3a.z, b3a.w, b3b.x, b3b.y, b3b.z, b3b.w};
#pragma unroll
    for (int kk = 0; kk < 8; kk++) {
      int w32;
      switch (kk >> 1) {
        case 0: w32 = a8.x; break;
        case 1: w32 = a8.y; break;
        case 2: w32 = a8.z; break;
        default: w32 = a8.w; break;
      }
      unsigned int u = (unsigned int)w32;
      unsigned int bits = (kk & 1) ? (u & 0xffff0000u) : (u << 16);
      float av = __uint_as_float(bits);
      ac0 += av * bv0[kk];
      ac1 += av * bv1[kk];
      ac2 += av * bv2[kk];
      ac3 += av * bv3[kk];
    }
  }
  float4 gb = *(const float4*)(gc_b + g0);
  float* yp = yg + (bh * 16 + row) * 16384 + p * 64 + g0;
  float4 o = make_float4(fmaxf(ac0 + gb.x, 0.0f), fmaxf(ac1 + gb.y, 0.0f),
                         fmaxf(ac2 + gb.z, 0.0f), fmaxf(ac3 + gb.w, 0.0f));
  *(float4*)yp = o;
}

// r0 GEMM partials: grid 256 = kc (Kc=64). Block computes full 64b x 256rh tile
// for its k-chunk via outer product; writes part[kc][b][rh].
__global__ __launch_bounds__(256) void k_r0(const float* __restrict__ yg,
    const float* __restrict__ r0_w, float* __restrict__ part) {
  __shared__ float ygs[64 * 68];   // ygT[k][b], row stride 68
  __shared__ float wts[64 * 260];  // wT[k][rh], row stride 260
  int kc = blockIdx.x, t = threadIdx.x;
  int k0 = kc * 64;
  // stage wT: c = t>>4 selects k-group (store lanes spread 32 banks), rr = t&15
  {
    int c = t >> 4, rr = t & 15;
    for (int rd = 0; rd < 16; rd++) {
      int rh = rd * 16 + rr;
      float4 v = *(const float4*)(r0_w + rh * 16384 + k0 + c * 4);
      wts[(4 * c + 0) * 260 + rh] = v.x;
      wts[(4 * c + 1) * 260 + rh] = v.y;
      wts[(4 * c + 2) * 260 + rh] = v.z;
      wts[(4 * c + 3) * 260 + rh] = v.w;
    }
  }
  // stage ygT
  {
    int b = t >> 2, kq = t & 3;
    const float* src = yg + b * 16384 + k0 + kq * 16;
#pragma unroll
    for (int u = 0; u < 4; u++) {
      float4 v = *(const float4*)(src + u * 4);
      int kk = kq * 16 + u * 4;
      ygs[(kk + 0) * 68 + b] = v.x;
      ygs[(kk + 1) * 68 + b] = v.y;
      ygs[(kk + 2) * 68 + b] = v.z;
      ygs[(kk + 3) * 68 + b] = v.w;
    }
  }
  __syncthreads();
  int lane = t & 63, wv = t >> 6;
  int b8 = lane & 7, r8 = lane >> 3;
  const float* yp = ygs + b8 * 8;
  const float* wp = wts + wv * 64 + r8 * 8;
  float acc[8][8];
#pragma unroll
  for (int i = 0; i < 8; i++)
#pragma unroll
    for (int j = 0; j < 8; j++) acc[i][j] = 0.0f;
#pragma unroll 2
  for (int k = 0; k < 64; k++) {
    float4 ya = *(const float4*)(yp + k * 68);
    float4 yb = *(const float4*)(yp + k * 68 + 4);
    float4 wa = *(const float4*)(wp + k * 260);
    float4 wb = *(const float4*)(wp + k * 260 + 4);
    float yv[8] = {ya.x, ya.y, ya.z, ya.w, yb.x, yb.y, yb.z, yb.w};
    float wr[8] = {wa.x, wa.y, wa.z, wa.w, wb.x, wb.y, wb.z, wb.w};
#pragma unroll
    for (int i = 0; i < 8; i++)
#pragma unroll
      for (int j = 0; j < 8; j++) acc[i][j] += yv[i] * wr[j];
  }
  float* pb = part + kc * 16384 + wv * 64 + r8 * 8;
#pragma unroll
  for (int i = 0; i < 8; i++) {
    float4 s0 = make_float4(acc[i][0], acc[i][1], acc[i][2], acc[i][3]);
    float4 s1 = make_float4(acc[i][4], acc[i][5], acc[i][6], acc[i][7]);
    float* pp = pb + (b8 * 8 + i) * 256;
    *(float4*)pp = s0;
    *(float4*)(pp + 4) = s1;
  }
}

// Reduce partials: grid 256 = (kq 4) x (oq 64). hbuf[o] += sum_{kc in kq} part[kc][o]
__global__ __launch_bounds__(256) void k_r0red(const float* __restrict__ part,
    float* __restrict__ hbuf) {
  int blk = blockIdx.x;
  int oq = blk & 63, kq = blk >> 6;
  int o = oq * 256 + threadIdx.x;
  float s = 0.0f;
  const float* pp = part + kq * 64 * 16384 + o;
#pragma unroll 8
  for (int kc = 0; kc < 64; kc++) s += pp[kc * 16384];
  atomicAdd(&hbuf[o], s);
}

// grid 256 = (bb, pq): wt for 64 p's, partial res over those p's -> res4[pq][b][g]
__global__ __launch_bounds__(256) void k_wt_res(const float* __restrict__ hbuf,
    const float* __restrict__ r3_w, const float* __restrict__ r3_b,
    const float* __restrict__ yg, float* __restrict__ res4) {
  __shared__ float hs[256];
  __shared__ float wts[64];
  __shared__ float red[256];
  int blk = blockIdx.x;
  int bb = blk >> 2, pq = blk & 3;
  int t = threadIdx.x;
  float hv = hbuf[bb * 256 + t];
  hs[t] = hv > 0.0f ? hv : 0.01f * hv;
  __syncthreads();
  int pl = t >> 2, c = t & 3;
  int pp = pq * 64 + pl;
  const float4* wrow = (const float4*)(r3_w + pp * 256 + c * 64);
  const float4* h4 = (const float4*)(hs) + c * 16;
  float a = 0.0f;
#pragma unroll
  for (int j = 0; j < 16; j++) {
    float4 w4 = wrow[j], hh = h4[j];
    a += hh.x * w4.x + hh.y * w4.y + hh.z * w4.z + hh.w * w4.w;
  }
  a += __shfl_xor(a, 1);
  a += __shfl_xor(a, 2);
  if (c == 0) wts[pl] = fmaxf(a + r3_b[pp], 0.0f);
  __syncthreads();
  int g = t & 63, ch = t >> 6;
  float r = 0.0f;
  const float* ygp = yg + bb * 16384 + pq * 4096 + g;
#pragma unroll
  for (int pi = 0; pi < 16; pi++) {
    int pl2 = ch * 16 + pi;
    r += wts[pl2] * ygp[pl2 * 64];
  }
  red[t] = r;
  __syncthreads();
  if (t < 64)
    res4[pq * 4096 + bb * 64 + t] = red[t] + red[t + 64] + red[t + 128] + red[t + 192];
}

// z = elu([sum(res4), x2] @ l1_w^T + l1_b); out = z @ l3_w^T + l3_b
__global__ __launch_bounds__(128) void k_final(const float* __restrict__ res4,
    const float* __restrict__ x2, const float* __restrict__ l1_w,
    const float* __restrict__ l1_b, const float* __restrict__ l3_w,
    const float* __restrict__ l3_b, float* __restrict__ out) {
  __shared__ float zs[128];
  int bb = blockIdx.x, t = threadIdx.x;
  float acc = l1_b[t];
  const float* wrow = l1_w + t * 72;
  const float* rr = res4 + bb * 64;
#pragma unroll 8
  for (int j = 0; j < 64; j++) {
    float rv = rr[j] + rr[4096 + j] + rr[8192 + j] + rr[12288 + j];
    acc += rv * wrow[j];
  }
  const float* xr = x2 + bb * 8;
#pragma unroll
  for (int j = 0; j < 8; j++) acc += xr[j] * wrow[64 + j];
  zs[t] = acc > 0.0f ? acc : expm1f(acc);
  __syncthreads();
  if (t < 9) {
    float o = l3_b[t];
    const float* w3 = l3_w + t * 128;
    for (int j = 0; j < 128; j++) o += zs[j] * w3[j];
    out[bb * 9 + t] = o;
  }
}

extern "C" void kernel_launch(void* const* d_in, const int* in_sizes, int n_in,
                              void* d_out, int out_size, void* d_ws, size_t ws_size,
                              hipStream_t stream) {
  (void)in_sizes; (void)n_in; (void)out_size; (void)ws_size;
  const float* x1     = (const float*)d_in[0];
  const float* x2     = (const float*)d_in[1];
  const float* conv_w = (const float*)d_in[2];
  const float* conv_b = (const float*)d_in[3];
  const float* k1_w   = (const float*)d_in[4];
  const float* k1_b   = (const float*)d_in[5];
  const float* k2_w   = (const float*)d_in[6];
  const float* k3_w   = (const float*)d_in[7];
  const float* k4_w   = (const float*)d_in[8];
  const float* k5_w   = (const float*)d_in[9];
  const float* k5_b   = (const float*)d_in[10];
  const float* gc_w   = (const float*)d_in[11];
  const float* gc_b   = (const float*)d_in[12];
  const float* r0_w   = (const float*)d_in[13];
  const float* r1_w   = (const float*)d_in[14];
  const float* r1_b   = (const float*)d_in[15];
  const float* r2_w   = (const float*)d_in[16];
  const float* r3_w   = (const float*)d_in[17];
  const float* r3_b   = (const float*)d_in[18];
  const float* l1_w   = (const float*)d_in[19];
  const float* l1_b   = (const float*)d_in[20];
  const float* l3_w   = (const float*)d_in[21];
  const float* l3_b   = (const float*)d_in[22];
  const float* ef     = (const float*)d_in[23];
  const float* linc   = (const float*)d_in[24];
  const float* rinc   = (const float*)d_in[25];
  const float* cap    = (const float*)d_in[26];
  const int*   pidx   = (const int*)d_in[27];
  float* out = (float*)d_out;

  float* ws   = (float*)d_ws;
  float* xbuf = ws + X_OFF;
  float* t4   = ws + T4_OFF;
  float* t3   = ws + T3_OFF;
  float* kb   = ws + KB_OFF;
  float* yg   = ws + YG_OFF;
  float* hbuf = ws + HB_OFF;
  float* res4 = ws + RES_OFF;
  float* part = ws + X_OFF;   // aliases x/t4/t3/kb (dead after k_eagg)
  int* ib = (int*)(ws + INT_OFF);
  int* lidx = ib;
  int* ridx = ib + 4096;
  int* part_start = ib + 8192;
  int* part_edges = ib + 8704;

  hipLaunchKernelGGL(k_decode, dim3(3072), dim3(256), 0, stream, linc, rinc, lidx, ridx);
  hipLaunchKernelGGL(k_lists, dim3(1), dim3(1024), 0, stream, lidx, part_start, part_edges);
  hipLaunchKernelGGL(k_conv, dim3(512), dim3(256), 0, stream, x1, conv_w, conv_b, xbuf);
  hipLaunchKernelGGL(k_prep, dim3(1856), dim3(256), 0, stream,
                     xbuf, pidx, k3_w, k4_w, x2, k2_w, ef, k1_w, k1_b,
                     r1_w, r1_b, r2_w, cap, t4, t3, kb, hbuf);
  hipLaunchKernelGGL(k_eagg, dim3(1024), dim3(256), 0, stream,
                     xbuf, kb, t3, t4, k5_w, k5_b, ridx, part_start, part_edges,
                     gc_w, gc_b, yg);
  hipLaunchKernelGGL(k_r0, dim3(256), dim3(256), 0, stream, yg, r0_w, part);
  hipLaunchKernelGGL(k_r0red, dim3(256), dim3(256), 0, stream, part, hbuf);
  hipLaunchKernelGGL(k_wt_res, dim3(256), dim3(256), 0, stream, hbuf, r3_w, r3_b, yg, res4);
  hipLaunchKernelGGL(k_final, dim3(64), dim3(128), 0, stream,
                     res4, x2, l1_w, l1_b, l3_w, l3_b, out);
}

// Round 2
// 268.455 us; speedup vs baseline: 1.2361x; 1.2361x over previous
//
#include <hip/hip_runtime.h>
#include <math.h>

#define B_ 64
#define N_ 512
#define P_ 256
#define E_ 4096
#define F_ 32
#define H_ 64
#define W_ 8
#define G_ 64
#define RH_ 256

// ---- workspace layout (float offsets) ----
#define X_OFF   0
#define T4_OFF  (X_OFF + N_*B_*F_)       // x:  [n][b][f]
#define T3_OFF  (T4_OFF + N_*B_*H_)      // t4: [n][b][h] (t2 folded in)
#define KB_OFF  (T3_OFF + P_*B_*H_)      // t3: [p][b][h]
#define KW_OFF  (KB_OFF + E_*H_)         // kb: [e][h]
#define YG_OFF  (KW_OFF + E_*B_*W_)      // (kw slot unused now, kept for layout stability)
#define HB_OFF  (YG_OFF + B_*P_*G_)      // yg: [b][p*64+g]
#define RES_OFF (HB_OFF + B_*RH_)        // hbuf: [b][rh]
#define INT_OFF (RES_OFF + 4*B_*G_)      // res4: [pq][b][g]
// int region at INT_OFF: lidx[4096] | ridx[4096] | part_start[512] | part_edges[4096]
// r0 partials (256*16384 floats = 16 MB) alias X_OFF.. (x/t4/t3/kb dead after k_eagg)

// ---------------------------------------------------------------------------
__global__ __launch_bounds__(256) void k_decode(const float* __restrict__ linc,
    const float* __restrict__ rinc, int* __restrict__ lidx, int* __restrict__ ridx) {
  int i4 = blockIdx.x * 256 + threadIdx.x;
  const int L4 = (P_ * E_) / 4;  // 262144
  if (i4 < L4) {
    float4 v = ((const float4*)linc)[i4];
    int i = i4 * 4;
    int p = i >> 12, e = i & 4095;
    if (v.x != 0.0f) lidx[e]     = p;
    if (v.y != 0.0f) lidx[e + 1] = p;
    if (v.z != 0.0f) lidx[e + 2] = p;
    if (v.w != 0.0f) lidx[e + 3] = p;
  } else {
    int j4 = i4 - L4;
    float4 v = ((const float4*)rinc)[j4];
    int j = j4 * 4;
    int e = j >> 9, n = j & 511;
    if (v.x != 0.0f) ridx[e] = n;
    if (v.y != 0.0f) ridx[e] = n + 1;
    if (v.z != 0.0f) ridx[e] = n + 2;
    if (v.w != 0.0f) ridx[e] = n + 3;
  }
}

// Counting-sort edges by partition. Single block of 1024.
__global__ __launch_bounds__(1024) void k_lists(const int* __restrict__ lidx,
    int* __restrict__ part_start, int* __restrict__ part_edges) {
  __shared__ int cnt[256];
  __shared__ int buf[256];
  __shared__ int cur[256];
  int t = threadIdx.x;
  if (t < 256) cnt[t] = 0;
  __syncthreads();
  for (int e = t; e < E_; e += 1024) atomicAdd(&cnt[lidx[e]], 1);
  __syncthreads();
  if (t < 256) buf[t] = cnt[t];
  __syncthreads();
  for (int off = 1; off < 256; off <<= 1) {
    int add = 0;
    if (t < 256 && t >= off) add = buf[t - off];
    __syncthreads();
    if (t < 256) buf[t] += add;
    __syncthreads();
  }
  if (t < 256) {
    part_start[t + 1] = buf[t];
    if (t == 0) part_start[0] = 0;
    cur[t] = buf[t] - cnt[t];
  }
  __syncthreads();
  for (int e = t; e < E_; e += 1024) {
    int p = lidx[e];
    int pos = atomicAdd(&cur[p], 1);
    part_edges[pos] = e;
  }
}

// Grouped conv (K=16, VALID, 1 out pos) + bias + relu -> x[n][b][f]
__global__ __launch_bounds__(256) void k_conv(const float* __restrict__ x1,
    const float* __restrict__ conv_w, const float* __restrict__ conv_b,
    float* __restrict__ x) {
  __shared__ float wsm[32 * 132];
  __shared__ float xsm[8192];
  int n = blockIdx.x, t = threadIdx.x;
  for (int i = t; i < 1024; i += 256) {
    int f = i >> 5, j = i & 31;
    ((float4*)wsm)[f * 33 + j] = ((const float4*)(conv_w + n * 4096))[i];
  }
  for (int i = t; i < 2048; i += 256) {
    int b = i >> 5, j = i & 31;
    ((float4*)xsm)[i] = ((const float4*)(x1 + b * 65536 + n * 128))[j];
  }
  __syncthreads();
  int f = t & 31, bq = t >> 5;
  float cb = conv_b[n * 32 + f];
  float acc[8];
#pragma unroll
  for (int bi = 0; bi < 8; bi++) acc[bi] = cb;
  const float4* wf4 = (const float4*)wsm + f * 33;
  const float4* xb4 = (const float4*)xsm + bq * 256;
#pragma unroll 4
  for (int k4 = 0; k4 < 32; k4++) {
    float4 wv = wf4[k4];
#pragma unroll
    for (int bi = 0; bi < 8; bi++) {
      float4 xv = xb4[bi * 32 + k4];
      acc[bi] += wv.x * xv.x + wv.y * xv.y + wv.z * xv.z + wv.w * xv.w;
    }
  }
#pragma unroll
  for (int bi = 0; bi < 8; bi++) {
    int b = bq * 8 + bi;
    x[n * 2048 + b * 32 + f] = fmaxf(acc[bi], 0.0f);
  }
}

// blocks [0,512): t4[n][b][h] = x[n]@k4_w^T + x2@k2_w^T
// blocks [512,768): t3[p][b][h] = x[pidx[p]]@k3_w^T
// blocks [768,1792): kb[e][h] = ef[e,:8]@k1_w^T + k1_b
// blocks [1792,1856): hbuf[b][rh] = x2@r1_w^T + r1_b + cap@r2_w^T
__global__ __launch_bounds__(256) void k_prep(
    const float* __restrict__ x, const int* __restrict__ pidx,
    const float* __restrict__ k3_w, const float* __restrict__ k4_w,
    const float* __restrict__ x2, const float* __restrict__ k2_w,
    const float* __restrict__ ef, const float* __restrict__ k1_w,
    const float* __restrict__ k1_b,
    const float* __restrict__ r1_w, const float* __restrict__ r1_b,
    const float* __restrict__ r2_w, const float* __restrict__ cap,
    float* __restrict__ t4, float* __restrict__ t3, float* __restrict__ kb,
    float* __restrict__ hbuf) {
  __shared__ float xsh[2048];
  __shared__ float wsh[64 * 36];
  __shared__ float x2s[512];
  __shared__ float k2s[512];
  int blk = blockIdx.x, t = threadIdx.x;
  if (blk < 768) {
    bool isT4 = blk < 512;
    int n = isT4 ? blk : pidx[blk - 512];
    const float* wmat = isT4 ? k4_w : k3_w;
    float* outp = isT4 ? (t4 + blk * 4096) : (t3 + (blk - 512) * 4096);
    for (int i = t; i < 512; i += 256) {
      ((float4*)xsh)[i] = ((const float4*)(x + n * 2048))[i];
      int h = i >> 3, j = i & 7;
      ((float4*)wsh)[h * 9 + j] = ((const float4*)wmat)[i];
    }
    if (isT4) {
      for (int i = t; i < 128; i += 256) {
        ((float4*)x2s)[i] = ((const float4*)x2)[i];
        ((float4*)k2s)[i] = ((const float4*)k2_w)[i];
      }
    }
    __syncthreads();
    int h = t & 63, bq = t >> 6;
    float wreg[32];
#pragma unroll
    for (int j = 0; j < 8; j++) {
      float4 v = ((float4*)wsh)[h * 9 + j];
      wreg[4 * j] = v.x; wreg[4 * j + 1] = v.y; wreg[4 * j + 2] = v.z; wreg[4 * j + 3] = v.w;
    }
    float w2[8];
    if (isT4) {
      float4 u = ((float4*)k2s)[h * 2], v = ((float4*)k2s)[h * 2 + 1];
      w2[0] = u.x; w2[1] = u.y; w2[2] = u.z; w2[3] = u.w;
      w2[4] = v.x; w2[5] = v.y; w2[6] = v.z; w2[7] = v.w;
    }
    for (int bi = 0; bi < 16; bi++) {
      int b = bq * 16 + bi;
      float acc = 0.0f;
#pragma unroll
      for (int j = 0; j < 8; j++) {
        float4 xv = ((float4*)xsh)[b * 8 + j];
        acc += xv.x * wreg[4 * j] + xv.y * wreg[4 * j + 1] +
               xv.z * wreg[4 * j + 2] + xv.w * wreg[4 * j + 3];
      }
      if (isT4) {
        float4 u = ((float4*)x2s)[b * 2], v = ((float4*)x2s)[b * 2 + 1];
        acc += u.x * w2[0] + u.y * w2[1] + u.z * w2[2] + u.w * w2[3] +
               v.x * w2[4] + v.y * w2[5] + v.z * w2[6] + v.w * w2[7];
      }
      outp[b * 64 + h] = acc;
    }
  } else if (blk < 1792) {
    int o = (blk - 768) * 256 + t;
    int e = o >> 6, h = o & 63;
    float acc = k1_b[h];
    const float* er = ef + e * 9;
    const float* kr = k1_w + h * 8;
#pragma unroll
    for (int d = 0; d < 8; d++) acc += er[d] * kr[d];
    kb[o] = acc;
  } else {
    int o = (blk - 1792) * 256 + t;
    int rh = o & 255;
    float acc = r1_b[rh];
    const float* xr = x2 + (o >> 8) * 8;
    const float* rr = r1_w + rh * 8;
#pragma unroll
    for (int d = 0; d < 8; d++) acc += xr[d] * rr[d];
    const float* r2r = r2_w + rh * 256;
    for (int p4 = 0; p4 < 64; p4++) {
      float4 cv = ((const float4*)cap)[p4];
      float4 rv = ((const float4*)r2r)[p4];
      acc += cv.x * rv.x + cv.y * rv.y + cv.z * rv.z + cv.w * rv.w;
    }
    hbuf[o] = acc;
  }
}

// Fused edge-MLP + aggregation + gc GEMM, one block (512 thr) per partition.
// Laneing: s = t&7 owns h in [s*8, s*8+8) and w = s; b = t>>3 is the batch row.
// k5_w slice (8w x 8h) + t3 fragment live in registers: ZERO LDS in main loop.
// h-reduction: 7-shfl reduce-scatter (3 levels) -> lane s holds kv for w=s.
// kb/t4 loads double-buffered one edge ahead; edge indices resolved 2 ahead.
// acc (32 f per thread, fp32) -> LDS fp32 [64b][256k] -> gc GEMM epilogue.
__global__ __launch_bounds__(512) void k_eagg(
    const float* __restrict__ x, const float* __restrict__ kb,
    const float* __restrict__ t3, const float* __restrict__ t4,
    const float* __restrict__ k5_w, const float* __restrict__ k5_b,
    const int* __restrict__ ridx, const int* __restrict__ part_start,
    const int* __restrict__ part_edges,
    const float* __restrict__ gc_w, const float* __restrict__ gc_b,
    float* __restrict__ yg) {
  __shared__ float accS[64 * 256];   // fp32 [b][k], f4-col ^ (b&7) swizzle (64 KB)
  int p = blockIdx.x, t = threadIdx.x;
  int s = t & 7, b = t >> 3;
  int h0 = s * 8;
  // hoist k5 slice [w][h0..h0+7] (64 regs) and t3 fragment (8 regs)
  float4 k5a[8], k5c[8];
#pragma unroll
  for (int w = 0; w < 8; w++) {
    k5a[w] = *(const float4*)(k5_w + w * 64 + h0);
    k5c[w] = *(const float4*)(k5_w + w * 64 + h0 + 4);
  }
  float kb5 = k5_b[s];
  float4 t3a = *(const float4*)(t3 + p * 4096 + b * 64 + h0);
  float4 t3b = *(const float4*)(t3 + p * 4096 + b * 64 + h0 + 4);
  float acc[32];
#pragma unroll
  for (int i = 0; i < 32; i++) acc[i] = 0.0f;
  int s0 = part_start[p], s1 = part_start[p + 1];
  if (s0 < s1) {
    // --- prologue: current edge loads + next edge loads ---
    int eC = part_edges[s0];
    int rCur = ridx[eC];
    float4 kbC0 = *(const float4*)(kb + eC * 64 + h0);
    float4 kbC1 = *(const float4*)(kb + eC * 64 + h0 + 4);
    float4 t4C0 = *(const float4*)(t4 + rCur * 4096 + b * 64 + h0);
    float4 t4C1 = *(const float4*)(t4 + rCur * 4096 + b * 64 + h0 + 4);
    int eN = (s0 + 1 < s1) ? part_edges[s0 + 1] : 0;
    int rNxt = (s0 + 1 < s1) ? ridx[eN] : 0;
    float4 kbN0 = *(const float4*)(kb + eN * 64 + h0);
    float4 kbN1 = *(const float4*)(kb + eN * 64 + h0 + 4);
    float4 t4N0 = *(const float4*)(t4 + rNxt * 4096 + b * 64 + h0);
    float4 t4N1 = *(const float4*)(t4 + rNxt * 4096 + b * 64 + h0 + 4);
    for (int idx = s0; idx < s1; idx++) {
      // resolve edge index 2 ahead (index chain hides under compute)
      int i2 = idx + 2;
      int e2 = (i2 < s1) ? part_edges[i2] : 0;
      int r2 = (i2 < s1) ? ridx[e2] : 0;
      // x row for current edge (consumed last; latency covered by kern+dot+shfl)
      const float4* xp = (const float4*)(x + rCur * 2048 + b * 32);
      float4 xv[8];
#pragma unroll
      for (int j = 0; j < 8; j++) xv[j] = xp[j];
      // kern + leaky(0.02) for this lane's 8 h
      float lk0, lk1, lk2, lk3, lk4, lk5, lk6, lk7, v;
      v = kbC0.x + t3a.x + t4C0.x; lk0 = v > 0.0f ? v : 0.02f * v;
      v = kbC0.y + t3a.y + t4C0.y; lk1 = v > 0.0f ? v : 0.02f * v;
      v = kbC0.z + t3a.z + t4C0.z; lk2 = v > 0.0f ? v : 0.02f * v;
      v = kbC0.w + t3a.w + t4C0.w; lk3 = v > 0.0f ? v : 0.02f * v;
      v = kbC1.x + t3b.x + t4C1.x; lk4 = v > 0.0f ? v : 0.02f * v;
      v = kbC1.y + t3b.y + t4C1.y; lk5 = v > 0.0f ? v : 0.02f * v;
      v = kbC1.z + t3b.z + t4C1.z; lk6 = v > 0.0f ? v : 0.02f * v;
      v = kbC1.w + t3b.w + t4C1.w; lk7 = v > 0.0f ? v : 0.02f * v;
      // partial dot: pw[w] over this lane's 8 h (64 FMA, all independent)
      float pw[8];
#pragma unroll
      for (int w = 0; w < 8; w++)
        pw[w] = lk0 * k5a[w].x + lk1 * k5a[w].y + lk2 * k5a[w].z + lk3 * k5a[w].w +
                lk4 * k5c[w].x + lk5 * k5c[w].y + lk6 * k5c[w].z + lk7 * k5c[w].w;
      // 7-shfl reduce-scatter over the 8 s-lanes: lane s ends with full sum for w=s
      int b0 = s & 1, b1 = s & 2, b2 = s & 4;
      float q0 = (b0 ? pw[1] : pw[0]) + __shfl_xor(b0 ? pw[0] : pw[1], 1);
      float q1 = (b0 ? pw[3] : pw[2]) + __shfl_xor(b0 ? pw[2] : pw[3], 1);
      float q2 = (b0 ? pw[5] : pw[4]) + __shfl_xor(b0 ? pw[4] : pw[5], 1);
      float q3 = (b0 ? pw[7] : pw[6]) + __shfl_xor(b0 ? pw[6] : pw[7], 1);
      float u0 = (b1 ? q1 : q0) + __shfl_xor(b1 ? q0 : q1, 2);
      float u1 = (b1 ? q3 : q2) + __shfl_xor(b1 ? q2 : q3, 2);
      float fv = (b2 ? u1 : u0) + __shfl_xor(b2 ? u0 : u1, 4);
      float kv = fmaxf(fv + kb5, 0.0f);
      // rank-1 accumulate: acc[f] += kv * x[rCur][b][f]
#pragma unroll
      for (int j = 0; j < 8; j++) {
        acc[4 * j + 0] += kv * xv[j].x;
        acc[4 * j + 1] += kv * xv[j].y;
        acc[4 * j + 2] += kv * xv[j].z;
        acc[4 * j + 3] += kv * xv[j].w;
      }
      // rotate double-buffer; issue loads for edge idx+2
      kbC0 = kbN0; kbC1 = kbN1; t4C0 = t4N0; t4C1 = t4N1;
      rCur = rNxt;
      kbN0 = *(const float4*)(kb + e2 * 64 + h0);
      kbN1 = *(const float4*)(kb + e2 * 64 + h0 + 4);
      t4N0 = *(const float4*)(t4 + r2 * 4096 + b * 64 + h0);
      t4N1 = *(const float4*)(t4 + r2 * 4096 + b * 64 + h0 + 4);
      rNxt = r2;
    }
  }
  // store acc (fp32) to LDS: thread's k-range = [s*32, s*32+32), col-swizzled
#pragma unroll
  for (int j = 0; j < 8; j++) {
    int col = (s * 8 + j) ^ (b & 7);
    *(float4*)(accS + b * 256 + col * 4) =
        make_float4(acc[4 * j], acc[4 * j + 1], acc[4 * j + 2], acc[4 * j + 3]);
  }
  __syncthreads();
  // epilogue: wave gq handles g in [gq*8, gq*8+8) for all 64 b (lane = b).
  // gc_w loads are wave-uniform (broadcast); accS reads swizzle-spread.
  int gq = t >> 6, be = t & 63;
  const float* gwb = gc_w + gq * 8 * 256;
  float ac[8];
#pragma unroll
  for (int i = 0; i < 8; i++) ac[i] = 0.0f;
  for (int k4 = 0; k4 < 64; k4++) {
    int col = k4 ^ (be & 7);
    float4 av = *(const float4*)(accS + be * 256 + col * 4);
#pragma unroll
    for (int i = 0; i < 8; i++) {
      float4 wv = *(const float4*)(gwb + i * 256 + k4 * 4);
      ac[i] += av.x * wv.x + av.y * wv.y + av.z * wv.z + av.w * wv.w;
    }
  }
  float* yp = yg + be * 16384 + p * 64 + gq * 8;
#pragma unroll
  for (int i = 0; i < 8; i++)
    yp[i] = fmaxf(ac[i] + gc_b[gq * 8 + i], 0.0f);
}

// r0 GEMM partials: grid 256 = kc (Kc=64). Block computes full 64b x 256rh tile
// for its k-chunk via outer product; writes part[kc][b][rh].
__global__ __launch_bounds__(256) void k_r0(const float* __restrict__ yg,
    const float* __restrict__ r0_w, float* __restrict__ part) {
  __shared__ float ygs[64 * 68];   // ygT[k][b], row stride 68
  __shared__ float wts[64 * 260];  // wT[k][rh], row stride 260
  int kc = blockIdx.x, t = threadIdx.x;
  int k0 = kc * 64;
  // stage wT: c = t>>4 selects k-group (store lanes spread 32 banks), rr = t&15
  {
    int c = t >> 4, rr = t & 15;
    for (int rd = 0; rd < 16; rd++) {
      int rh = rd * 16 + rr;
      float4 v = *(const float4*)(r0_w + rh * 16384 + k0 + c * 4);
      wts[(4 * c + 0) * 260 + rh] = v.x;
      wts[(4 * c + 1) * 260 + rh] = v.y;
      wts[(4 * c + 2) * 260 + rh] = v.z;
      wts[(4 * c + 3) * 260 + rh] = v.w;
    }
  }
  // stage ygT
  {
    int b = t >> 2, kq = t & 3;
    const float* src = yg + b * 16384 + k0 + kq * 16;
#pragma unroll
    for (int u = 0; u < 4; u++) {
      float4 v = *(const float4*)(src + u * 4);
      int kk = kq * 16 + u * 4;
      ygs[(kk + 0) * 68 + b] = v.x;
      ygs[(kk + 1) * 68 + b] = v.y;
      ygs[(kk + 2) * 68 + b] = v.z;
      ygs[(kk + 3) * 68 + b] = v.w;
    }
  }
  __syncthreads();
  int lane = t & 63, wv = t >> 6;
  int b8 = lane & 7, r8 = lane >> 3;
  const float* yp = ygs + b8 * 8;
  const float* wp = wts + wv * 64 + r8 * 8;
  float acc[8][8];
#pragma unroll
  for (int i = 0; i < 8; i++)
#pragma unroll
    for (int j = 0; j < 8; j++) acc[i][j] = 0.0f;
#pragma unroll 2
  for (int k = 0; k < 64; k++) {
    float4 ya = *(const float4*)(yp + k * 68);
    float4 yb = *(const float4*)(yp + k * 68 + 4);
    float4 wa = *(const float4*)(wp + k * 260);
    float4 wb = *(const float4*)(wp + k * 260 + 4);
    float yv[8] = {ya.x, ya.y, ya.z, ya.w, yb.x, yb.y, yb.z, yb.w};
    float wr[8] = {wa.x, wa.y, wa.z, wa.w, wb.x, wb.y, wb.z, wb.w};
#pragma unroll
    for (int i = 0; i < 8; i++)
#pragma unroll
      for (int j = 0; j < 8; j++) acc[i][j] += yv[i] * wr[j];
  }
  float* pb = part + kc * 16384 + wv * 64 + r8 * 8;
#pragma unroll
  for (int i = 0; i < 8; i++) {
    float4 s0 = make_float4(acc[i][0], acc[i][1], acc[i][2], acc[i][3]);
    float4 s1 = make_float4(acc[i][4], acc[i][5], acc[i][6], acc[i][7]);
    float* pp = pb + (b8 * 8 + i) * 256;
    *(float4*)pp = s0;
    *(float4*)(pp + 4) = s1;
  }
}

// Reduce partials: grid 256 = (kq 4) x (oq 64). hbuf[o] += sum_{kc in kq} part[kc][o]
__global__ __launch_bounds__(256) void k_r0red(const float* __restrict__ part,
    float* __restrict__ hbuf) {
  int blk = blockIdx.x;
  int oq = blk & 63, kq = blk >> 6;
  int o = oq * 256 + threadIdx.x;
  float s = 0.0f;
  const float* pp = part + kq * 64 * 16384 + o;
#pragma unroll 8
  for (int kc = 0; kc < 64; kc++) s += pp[kc * 16384];
  atomicAdd(&hbuf[o], s);
}

// grid 256 = (bb, pq): wt for 64 p's, partial res over those p's -> res4[pq][b][g]
__global__ __launch_bounds__(256) void k_wt_res(const float* __restrict__ hbuf,
    const float* __restrict__ r3_w, const float* __restrict__ r3_b,
    const float* __restrict__ yg, float* __restrict__ res4) {
  __shared__ float hs[256];
  __shared__ float wts[64];
  __shared__ float red[256];
  int blk = blockIdx.x;
  int bb = blk >> 2, pq = blk & 3;
  int t = threadIdx.x;
  float hv = hbuf[bb * 256 + t];
  hs[t] = hv > 0.0f ? hv : 0.01f * hv;
  __syncthreads();
  int pl = t >> 2, c = t & 3;
  int pp = pq * 64 + pl;
  const float4* wrow = (const float4*)(r3_w + pp * 256 + c * 64);
  const float4* h4 = (const float4*)(hs) + c * 16;
  float a = 0.0f;
#pragma unroll
  for (int j = 0; j < 16; j++) {
    float4 w4 = wrow[j], hh = h4[j];
    a += hh.x * w4.x + hh.y * w4.y + hh.z * w4.z + hh.w * w4.w;
  }
  a += __shfl_xor(a, 1);
  a += __shfl_xor(a, 2);
  if (c == 0) wts[pl] = fmaxf(a + r3_b[pp], 0.0f);
  __syncthreads();
  int g = t & 63, ch = t >> 6;
  float r = 0.0f;
  const float* ygp = yg + bb * 16384 + pq * 4096 + g;
#pragma unroll
  for (int pi = 0; pi < 16; pi++) {
    int pl2 = ch * 16 + pi;
    r += wts[pl2] * ygp[pl2 * 64];
  }
  red[t] = r;
  __syncthreads();
  if (t < 64)
    res4[pq * 4096 + bb * 64 + t] = red[t] + red[t + 64] + red[t + 128] + red[t + 192];
}

// z = elu([sum(res4), x2] @ l1_w^T + l1_b); out = z @ l3_w^T + l3_b
__global__ __launch_bounds__(128) void k_final(const float* __restrict__ res4,
    const float* __restrict__ x2, const float* __restrict__ l1_w,
    const float* __restrict__ l1_b, const float* __restrict__ l3_w,
    const float* __restrict__ l3_b, float* __restrict__ out) {
  __shared__ float zs[128];
  int bb = blockIdx.x, t = threadIdx.x;
  float acc = l1_b[t];
  const float* wrow = l1_w + t * 72;
  const float* rr = res4 + bb * 64;
#pragma unroll 8
  for (int j = 0; j < 64; j++) {
    float rv = rr[j] + rr[4096 + j] + rr[8192 + j] + rr[12288 + j];
    acc += rv * wrow[j];
  }
  const float* xr = x2 + bb * 8;
#pragma unroll
  for (int j = 0; j < 8; j++) acc += xr[j] * wrow[64 + j];
  zs[t] = acc > 0.0f ? acc : expm1f(acc);
  __syncthreads();
  if (t < 9) {
    float o = l3_b[t];
    const float* w3 = l3_w + t * 128;
    for (int j = 0; j < 128; j++) o += zs[j] * w3[j];
    out[bb * 9 + t] = o;
  }
}

extern "C" void kernel_launch(void* const* d_in, const int* in_sizes, int n_in,
                              void* d_out, int out_size, void* d_ws, size_t ws_size,
                              hipStream_t stream) {
  (void)in_sizes; (void)n_in; (void)out_size; (void)ws_size;
  const float* x1     = (const float*)d_in[0];
  const float* x2     = (const float*)d_in[1];
  const float* conv_w = (const float*)d_in[2];
  const float* conv_b = (const float*)d_in[3];
  const float* k1_w   = (const float*)d_in[4];
  const float* k1_b   = (const float*)d_in[5];
  const float* k2_w   = (const float*)d_in[6];
  const float* k3_w   = (const float*)d_in[7];
  const float* k4_w   = (const float*)d_in[8];
  const float* k5_w   = (const float*)d_in[9];
  const float* k5_b   = (const float*)d_in[10];
  const float* gc_w   = (const float*)d_in[11];
  const float* gc_b   = (const float*)d_in[12];
  const float* r0_w   = (const float*)d_in[13];
  const float* r1_w   = (const float*)d_in[14];
  const float* r1_b   = (const float*)d_in[15];
  const float* r2_w   = (const float*)d_in[16];
  const float* r3_w   = (const float*)d_in[17];
  const float* r3_b   = (const float*)d_in[18];
  const float* l1_w   = (const float*)d_in[19];
  const float* l1_b   = (const float*)d_in[20];
  const float* l3_w   = (const float*)d_in[21];
  const float* l3_b   = (const float*)d_in[22];
  const float* ef     = (const float*)d_in[23];
  const float* linc   = (const float*)d_in[24];
  const float* rinc   = (const float*)d_in[25];
  const float* cap    = (const float*)d_in[26];
  const int*   pidx   = (const int*)d_in[27];
  float* out = (float*)d_out;

  float* ws   = (float*)d_ws;
  float* xbuf = ws + X_OFF;
  float* t4   = ws + T4_OFF;
  float* t3   = ws + T3_OFF;
  float* kb   = ws + KB_OFF;
  float* yg   = ws + YG_OFF;
  float* hbuf = ws + HB_OFF;
  float* res4 = ws + RES_OFF;
  float* part = ws + X_OFF;   // aliases x/t4/t3/kb (dead after k_eagg)
  int* ib = (int*)(ws + INT_OFF);
  int* lidx = ib;
  int* ridx = ib + 4096;
  int* part_start = ib + 8192;
  int* part_edges = ib + 8704;

  hipLaunchKernelGGL(k_decode, dim3(3072), dim3(256), 0, stream, linc, rinc, lidx, ridx);
  hipLaunchKernelGGL(k_lists, dim3(1), dim3(1024), 0, stream, lidx, part_start, part_edges);
  hipLaunchKernelGGL(k_conv, dim3(512), dim3(256), 0, stream, x1, conv_w, conv_b, xbuf);
  hipLaunchKernelGGL(k_prep, dim3(1856), dim3(256), 0, stream,
                     xbuf, pidx, k3_w, k4_w, x2, k2_w, ef, k1_w, k1_b,
                     r1_w, r1_b, r2_w, cap, t4, t3, kb, hbuf);
  hipLaunchKernelGGL(k_eagg, dim3(256), dim3(512), 0, stream,
                     xbuf, kb, t3, t4, k5_w, k5_b, ridx, part_start, part_edges,
                     gc_w, gc_b, yg);
  hipLaunchKernelGGL(k_r0, dim3(256), dim3(256), 0, stream, yg, r0_w, part);
  hipLaunchKernelGGL(k_r0red, dim3(256), dim3(256), 0, stream, part, hbuf);
  hipLaunchKernelGGL(k_wt_res, dim3(256), dim3(256), 0, stream, hbuf, r3_w, r3_b, yg, res4);
  hipLaunchKernelGGL(k_final, dim3(64), dim3(128), 0, stream,
                     res4, x2, l1_w, l1_b, l3_w, l3_b, out);
}